// Round 5
// baseline (364.372 us; speedup 1.0000x reference)
//
#include <hip/hip_runtime.h>

#define N_NODES 50000
#define N_EDGES 800000
#define IN_DIM  128
#define HID_DIM 256
#define OUT_DIM 128
#define BUCKET_CAP 64    // in-degree ~ Poisson(16); P(deg>64) ~ 2e-18 over 50k nodes
#define NCOARSE 391      // ceil(50000/128) coarse bins of 128 dst nodes
#define BINSZ 128        // nodes per coarse bin
#define CHUNK 4000       // edges per binning block
#define NBLK1 200        // 200 * 4000 = 800000
#define SEGCAP 32        // per-(block,bin) capacity: Poisson(10.24) + ~6.8 sigma
#define HLD 264          // LDS row stride (ushorts) for H tile: 256 + 8 pad
#define GROWS 64         // rows per gemm12 block
#define NQBLK 12500      // gather blocks per quarter phase (12500*4 nodes = 50000)

typedef __attribute__((ext_vector_type(8))) short short8;
typedef __attribute__((ext_vector_type(4))) float f32x4;

// ---- bf16 helpers (RNE) ----
__device__ inline ushort f2b(float f) {
    union { float f; unsigned u; } v; v.f = f;
    return (ushort)((v.u + 0x7FFFu + ((v.u >> 16) & 1u)) >> 16);
}
__device__ inline float b2f(ushort h) {
    union { unsigned u; float f; } v; v.u = ((unsigned)h) << 16;
    return v.f;
}
__device__ inline float2 u2f2(unsigned u) {
    float2 r; r.x = b2f((ushort)(u & 0xFFFFu)); r.y = b2f((ushort)(u >> 16)); return r;
}
__device__ inline unsigned f2u2(float a, float b) {
    return (unsigned)f2b(a) | ((unsigned)f2b(b) << 16);
}

// ---------------- prep: conv_x || conv_w || edge binning (+degree atomics) ----------------
// Round-1 lesson: global-atomic bucket SCATTER costs 65us (write-amp); the
// counter atomicAdd alone is cheap (L2-resident 200KB, latency-hidden).
// Round-3 lesson: never multiply per-wave prologue cost (channel-split waves).
// Round-4 lesson: within-bucket src-sort is neutral -> locality must come from
// grid-level phasing, not per-wave access order.

__global__ __launch_bounds__(256) void prep_kernel(const float* __restrict__ x,
                                                   const float* __restrict__ W1,
                                                   const float* __restrict__ W2,
                                                   const int* __restrict__ src,
                                                   const int* __restrict__ dst,
                                                   ushort* __restrict__ xb,
                                                   ushort* __restrict__ w1t,
                                                   ushort* __restrict__ w2t,
                                                   int* __restrict__ cnt,
                                                   int* __restrict__ bcnt,
                                                   int* __restrict__ binbuf) {
    __shared__ int vals[CHUNK];           // 16 KB: (src<<7)|(dst&127)
    __shared__ ushort lpos[CHUNK];        // 8 KB
    __shared__ ushort lbin[CHUNK];        // 8 KB
    __shared__ int hist[NCOARSE];
    const int b = blockIdx.x;
    const int t = threadIdx.x;
    if (b < 6250) {
        int i = b * 256 + t;               // over N*128/4 float4s
        float4 v = ((const float4*)x)[i];
        ushort4 o; o.x = f2b(v.x); o.y = f2b(v.y); o.z = f2b(v.z); o.w = f2b(v.w);
        ((ushort4*)xb)[i] = o;
    } else if (b < 6506) {
        int i = (b - 6250) * 256 + t;      // 65536 total
        if (i < 32768) {
            int n = i >> 7, k = i & 127;
            w1t[i] = f2b(W1[k * HID_DIM + n]);
        } else {
            int j = i - 32768;
            int n = j >> 8, k = j & 255;
            w2t[j] = f2b(W2[k * OUT_DIM + n]);
        }
    } else {
        const int blk = b - 6506;
        const int e0 = blk * CHUNK;
        for (int i = t; i < NCOARSE; i += 256) hist[i] = 0;
        __syncthreads();
        for (int i = t; i < CHUNK; i += 256) {
            int s = src[e0 + i], d = dst[e0 + i];
            atomicAdd(&cnt[d], 1);         // true in-degree (for dinv)
            int bin = d >> 7;              // 128-node bins
            vals[i] = (s << 7) | (d & 127);
            lbin[i] = (ushort)bin;
            lpos[i] = (ushort)atomicAdd(&hist[bin], 1);
        }
        __syncthreads();
        for (int i = t; i < NCOARSE; i += 256) {
            int h = hist[i]; if (h > SEGCAP) h = SEGCAP;
            bcnt[i * NBLK1 + blk] = h;
        }
        for (int i = t; i < CHUNK; i += 256) {
            int bin = lbin[i];
            int p = lpos[i];
            if (p < SEGCAP) binbuf[((size_t)bin * NBLK1 + blk) * SEGCAP + p] = vals[i];
        }
    }
}

// ---------------- dinv: tiny elementwise kernel (needed before binpass2) ----------------

__global__ __launch_bounds__(256) void dinv_kernel(const int* __restrict__ cnt,
                                                   float* __restrict__ dinv) {
    int i = blockIdx.x * 256 + threadIdx.x;
    if (i < N_NODES) dinv[i] = rsqrtf((float)cnt[i] + 1.0f);
}

// ---------------- binpass2: buckets (u16 src) + per-slot norms (f32) ----------------
// norm[slot] = dinv[src]*dinv[dst] for valid slots, 0 for padding -> quarter-
// gathers need no guards and no random dinv[src] reads.

__global__ __launch_bounds__(256) void binpass2_kernel(const int* __restrict__ bcnt,
                                                       const int* __restrict__ binbuf,
                                                       const float* __restrict__ dinv,
                                                       ushort* __restrict__ bucket,
                                                       float* __restrict__ normbuf) {
    __shared__ int lcnt[BINSZ];
    __shared__ int lm[NBLK1];
    __shared__ float ldv[BINSZ];
    __shared__ ushort lbuck[BINSZ * BUCKET_CAP];   // 16 KB
    const int bin = blockIdx.x;
    const int t = threadIdx.x;
    const int node0 = bin * BINSZ;
    if (t < BINSZ) {
        lcnt[t] = 0;
        int nd = node0 + t;
        ldv[t] = nd < N_NODES ? dinv[nd] : 0.f;
    }
    if (t < NBLK1) lm[t] = bcnt[bin * NBLK1 + t];
    __syncthreads();
    const int* bb = binbuf + (size_t)bin * NBLK1 * SEGCAP;
    for (int f = t; f < NBLK1 * SEGCAP; f += 256) {
        int blk = f >> 5;        // SEGCAP = 32
        int sl = f & 31;
        if (sl < lm[blk]) {
            int v = bb[f];
            int dl = v & 127;
            int pos = atomicAdd(&lcnt[dl], 1);
            if (pos < BUCKET_CAP) lbuck[dl * BUCKET_CAP + pos] = (ushort)(v >> 7);
        }
    }
    __syncthreads();
    for (int idx = t; idx < BINSZ * BUCKET_CAP; idx += 256) {
        int node = idx >> 6, sl = idx & 63;
        int nd = node0 + node;
        if (nd >= N_NODES) break;
        int c = lcnt[node]; if (c > BUCKET_CAP) c = BUCKET_CAP;
        bool val = sl < c;
        ushort s = val ? lbuck[idx] : (ushort)0;
        float nm = val ? dinv[s] * ldv[node] : 0.f;
        size_t g = (size_t)nd * BUCKET_CAP + sl;
        bucket[g] = s;
        normbuf[g] = nm;
    }
}

// ---------------- gather0: aggx = Ahat * x, quarter-phased ----------------
// Phase q (= bid/NQBLK, so co-dispatched blocks share it) reads ONLY channels
// [32q,32q+32): a 3.2 MB slice of xb that fits each XCD's 4 MB L2.
// Wave = one (node, quarter): lane = (e:4 slots)<<4 | (c:16 dword chunks).
// Padding slots have norm 0 (and src 0 -> safe in-bounds dummy read).

__global__ __launch_bounds__(256) void gather0_kernel(const int* __restrict__ cnt,
                                                      const ushort* __restrict__ bucket,
                                                      const float* __restrict__ normbuf,
                                                      const float* __restrict__ dinv,
                                                      const ushort* __restrict__ xb,
                                                      ushort* __restrict__ aggxb) {
    const int bid = blockIdx.x;
    const int q = bid / NQBLK;
    const int w = (bid % NQBLK) * 4 + (threadIdx.x >> 6);
    const int lane = threadIdx.x & 63;
    const int e = lane >> 4;         // edge slot 0..3
    const int c = lane & 15;         // dword chunk (2 channels)
    int ctv = cnt[w];
    int n = ctv > BUCKET_CAP ? BUCKET_CAP : ctv;
    int sv = (int)bucket[(size_t)w * BUCKET_CAP + lane];
    float nv = normbuf[(size_t)w * BUCKET_CAP + lane];
    const ushort* xs = xb + q * 32 + c * 2;     // slice + chunk offset
    float2 acc = {0.f, 0.f};
    const int nr = (n + 3) & ~3;
    for (int it = 0; it < nr; it += 4) {
        int s = __shfl(sv, it + e);
        float f = __shfl(nv, it + e);
        float2 v = u2f2(*(const unsigned*)(xs + (size_t)s * IN_DIM));
        acc.x += v.x * f; acc.y += v.y * f;
    }
    acc.x += __shfl_down(acc.x, 32); acc.y += __shfl_down(acc.y, 32);
    acc.x += __shfl_down(acc.x, 16); acc.y += __shfl_down(acc.y, 16);
    if (lane < 16) {
        float dd = dinv[w], sd = dd * dd;
        float2 sx = u2f2(*(const unsigned*)(xs + (size_t)w * IN_DIM));
        acc.x += sx.x * sd; acc.y += sx.y * sd;
        *(unsigned*)(aggxb + (size_t)w * IN_DIM + q * 32 + lane * 2) = f2u2(acc.x, acc.y);
    }
}

// ---------------- gemm12 (MFMA, fused): h2b = (relu(aggx@W1 + b1)) @ W2 ----------------
// Block = 64 rows, 4 waves; B-fragments hoisted; __launch_bounds__(256,2).

__global__ __launch_bounds__(256, 2) void gemm12_mfma(const ushort* __restrict__ aggxb,
                                                      const ushort* __restrict__ w1t,
                                                      const float* __restrict__ b1,
                                                      const ushort* __restrict__ w2t,
                                                      ushort* __restrict__ h2b) {
    __shared__ ushort Hs[GROWS * HLD];   // 33 KB
    const int row0 = blockIdx.x * GROWS;
    const int wv = threadIdx.x >> 6;
    const int lane = threadIdx.x & 63;
    const int l15 = lane & 15, q = lane >> 4;

    // ---- phase 1: H = relu(aggx @ W1 + b1) -> LDS ----
    short8 bf1[16];
#pragma unroll
    for (int kb = 0; kb < 4; ++kb)
#pragma unroll
        for (int t = 0; t < 4; ++t) {
            int col = wv * 64 + t * 16 + l15;
            bf1[kb * 4 + t] = *(const short8*)(w1t + (size_t)col * IN_DIM + kb * 32 + q * 8);
        }
    short8 af[4][4];
#pragma unroll
    for (int sub = 0; sub < 4; ++sub) {
        int ar = row0 + sub * 16 + l15;
        if (ar >= N_NODES) ar = N_NODES - 1;
        const ushort* ab = aggxb + (size_t)ar * IN_DIM + q * 8;
#pragma unroll
        for (int kb = 0; kb < 4; ++kb) af[sub][kb] = *(const short8*)(ab + kb * 32);
    }
    f32x4 acc1[4][4] = {};
#pragma unroll
    for (int sub = 0; sub < 4; ++sub)
#pragma unroll
        for (int kb = 0; kb < 4; ++kb)
#pragma unroll
            for (int t = 0; t < 4; ++t)
                acc1[sub][t] = __builtin_amdgcn_mfma_f32_16x16x32_bf16(
                    af[sub][kb], bf1[kb * 4 + t], acc1[sub][t], 0, 0, 0);
#pragma unroll
    for (int t = 0; t < 4; ++t) {
        int col = wv * 64 + t * 16 + l15;
        float bias = b1[col];
#pragma unroll
        for (int sub = 0; sub < 4; ++sub)
#pragma unroll
            for (int r = 0; r < 4; ++r) {
                int row = sub * 16 + q * 4 + r;
                float v = acc1[sub][t][r] + bias;
                Hs[row * HLD + col] = f2b(v > 0.f ? v : 0.f);
            }
    }
    __syncthreads();

    // ---- phase 2: h2 = H @ W2 (A from LDS, B hoisted) ----
    short8 bf2[16];
#pragma unroll
    for (int kb = 0; kb < 8; ++kb)
#pragma unroll
        for (int t = 0; t < 2; ++t) {
            int col = wv * 32 + t * 16 + l15;
            bf2[kb * 2 + t] = *(const short8*)(w2t + (size_t)col * HID_DIM + kb * 32 + q * 8);
        }
    f32x4 acc2[4][2] = {};
#pragma unroll
    for (int sub = 0; sub < 4; ++sub) {
        const ushort* hb = Hs + (sub * 16 + l15) * HLD + q * 8;
#pragma unroll
        for (int kb = 0; kb < 8; ++kb) {
            short8 a = *(const short8*)(hb + kb * 32);
#pragma unroll
            for (int t = 0; t < 2; ++t)
                acc2[sub][t] = __builtin_amdgcn_mfma_f32_16x16x32_bf16(
                    a, bf2[kb * 2 + t], acc2[sub][t], 0, 0, 0);
        }
    }
#pragma unroll
    for (int sub = 0; sub < 4; ++sub)
#pragma unroll
        for (int t = 0; t < 2; ++t) {
            int col = wv * 32 + t * 16 + l15;
#pragma unroll
            for (int r = 0; r < 4; ++r) {
                int row = row0 + sub * 16 + q * 4 + r;
                if (row < N_NODES)
                    h2b[(size_t)row * OUT_DIM + col] = f2b(acc2[sub][t][r]);
            }
        }
}

// ---------------- gather2: out = Ahat * h2 + b2, quarter-phased ----------------

__global__ __launch_bounds__(256) void gather2_kernel(const int* __restrict__ cnt,
                                                      const ushort* __restrict__ bucket,
                                                      const float* __restrict__ normbuf,
                                                      const float* __restrict__ dinv,
                                                      const ushort* __restrict__ h2b,
                                                      const float* __restrict__ b2,
                                                      float* __restrict__ out) {
    const int bid = blockIdx.x;
    const int q = bid / NQBLK;
    const int w = (bid % NQBLK) * 4 + (threadIdx.x >> 6);
    const int lane = threadIdx.x & 63;
    const int e = lane >> 4;
    const int c = lane & 15;
    int ctv = cnt[w];
    int n = ctv > BUCKET_CAP ? BUCKET_CAP : ctv;
    int sv = (int)bucket[(size_t)w * BUCKET_CAP + lane];
    float nv = normbuf[(size_t)w * BUCKET_CAP + lane];
    const ushort* hs = h2b + q * 32 + c * 2;
    float2 acc = {0.f, 0.f};
    const int nr = (n + 3) & ~3;
    for (int it = 0; it < nr; it += 4) {
        int s = __shfl(sv, it + e);
        float f = __shfl(nv, it + e);
        float2 v = u2f2(*(const unsigned*)(hs + (size_t)s * OUT_DIM));
        acc.x += v.x * f; acc.y += v.y * f;
    }
    acc.x += __shfl_down(acc.x, 32); acc.y += __shfl_down(acc.y, 32);
    acc.x += __shfl_down(acc.x, 16); acc.y += __shfl_down(acc.y, 16);
    if (lane < 16) {
        float dd = dinv[w], sd = dd * dd;
        float2 sx = u2f2(*(const unsigned*)(hs + (size_t)w * OUT_DIM));
        float2 bb = *(const float2*)(b2 + q * 32 + lane * 2);
        acc.x += sx.x * sd + bb.x;
        acc.y += sx.y * sd + bb.y;
        *(float2*)(out + (size_t)w * OUT_DIM + q * 32 + lane * 2) = acc;
    }
}

extern "C" void kernel_launch(void* const* d_in, const int* in_sizes, int n_in,
                              void* d_out, int out_size, void* d_ws, size_t ws_size,
                              hipStream_t stream) {
    const float* x  = (const float*)d_in[0];
    const int*   ei = (const int*)d_in[1];
    const float* W1 = (const float*)d_in[2];
    const float* b1 = (const float*)d_in[3];
    const float* W2 = (const float*)d_in[4];
    const float* b2 = (const float*)d_in[5];
    float* out = (float*)d_out;

    const int* src = ei;             // edge_index[0]
    const int* dst = ei + N_EDGES;   // edge_index[1]

    // workspace layout (bytes):
    //  bcnt    : [0, 312800)               int[391*200]
    //  cnt     : [320000, 520000)          int[50000]
    //  dinv    : [520000, 720000)          float[50000]
    //  bucket  : [720000, 7120000)         ushort[50000*64]
    //  normbuf : [7120000, 19920000)       float[50000*64] (0 on padding slots)
    //  binbuf  : [19920000, 29929600)      int[391*200*32]
    //  xb      : [29932800, 42732800)      bf16[50000*128]
    //  w1t     : [42732800, 42798336)      bf16[256*128]
    //  w2t     : [42798336, 42863872)      bf16[128*256]
    //  aggxb   : [42863872, 55663872)      bf16[50000*128]
    //  h2b     : [55663872, 68463872)      bf16[50000*128]
    char* ws = (char*)d_ws;
    int*    bcnt    = (int*)(ws);
    int*    cnt     = (int*)(ws + 320000);
    float*  dinv    = (float*)(ws + 520000);
    ushort* bucket  = (ushort*)(ws + 720000);
    float*  normbuf = (float*)(ws + 7120000);
    int*    binbuf  = (int*)(ws + 19920000);
    ushort* xb      = (ushort*)(ws + 29932800);
    ushort* w1t     = (ushort*)(ws + 42732800);
    ushort* w2t     = (ushort*)(ws + 42798336);
    ushort* aggxb   = (ushort*)(ws + 42863872);
    ushort* h2b     = (ushort*)(ws + 55663872);

    hipMemsetAsync(cnt, 0, N_NODES * sizeof(int), stream);

    // prep (conv_x || conv_w || binning + degree atomics)
    prep_kernel<<<6706, 256, 0, stream>>>(x, W1, W2, src, dst, xb, w1t, w2t,
                                          cnt, bcnt, binbuf);
    dinv_kernel<<<196, 256, 0, stream>>>(cnt, dinv);
    binpass2_kernel<<<NCOARSE, 256, 0, stream>>>(bcnt, binbuf, dinv, bucket, normbuf);

    // layer 1 aggregate (quarter-phased, L2-slice-pinned), fused transform L1+L2
    gather0_kernel<<<4 * NQBLK, 256, 0, stream>>>(cnt, bucket, normbuf, dinv, xb, aggxb);
    gemm12_mfma<<<(N_NODES + GROWS - 1) / GROWS, 256, 0, stream>>>(aggxb, w1t, b1, w2t, h2b);

    // layer 2 aggregate (quarter-phased, self-loop + b2 fused)
    gather2_kernel<<<4 * NQBLK, 256, 0, stream>>>(cnt, bucket, normbuf, dinv, h2b, b2, out);
}

// Round 6
// 235.813 us; speedup vs baseline: 1.5452x; 1.5452x over previous
//
#include <hip/hip_runtime.h>

#define N_NODES 50000
#define N_EDGES 800000
#define IN_DIM  128
#define HID_DIM 256
#define OUT_DIM 128
#define BUCKET_CAP 64    // in-degree ~ Poisson(16); P(deg>64) ~ 2e-18 over 50k nodes
#define NCOARSE 391      // ceil(50000/128) coarse bins of 128 dst nodes
#define BINSZ 128        // nodes per coarse bin
#define CHUNK 4000       // edges per binning block
#define NBLK1 200        // 200 * 4000 = 800000
#define SEGCAP 32        // per-(block,bin) capacity: Poisson(10.24) + ~6.8 sigma
#define HLD 264          // LDS row stride (ushorts) for H tile: 256 + 8 pad
#define AXLD 136         // LDS row stride (ushorts) for aggx tile: 128 + 8 pad (272B, 16B-aligned)
#define GROWS 64         // rows per gemm block

typedef __attribute__((ext_vector_type(8))) short short8;
typedef __attribute__((ext_vector_type(4))) float f32x4;

// ---- bf16 helpers (RNE) ----
__device__ inline ushort f2b(float f) {
    union { float f; unsigned u; } v; v.f = f;
    return (ushort)((v.u + 0x7FFFu + ((v.u >> 16) & 1u)) >> 16);
}
__device__ inline float b2f(ushort h) {
    union { unsigned u; float f; } v; v.u = ((unsigned)h) << 16;
    return v.f;
}
__device__ inline float2 u2f2(unsigned u) {
    float2 r; r.x = b2f((ushort)(u & 0xFFFFu)); r.y = b2f((ushort)(u >> 16)); return r;
}
__device__ inline unsigned f2u2(float a, float b) {
    return (unsigned)f2b(a) | ((unsigned)f2b(b) << 16);
}
__device__ inline void fma8(float2* acc, uint4 u, float n) {
    float2 v0 = u2f2(u.x), v1 = u2f2(u.y), v2 = u2f2(u.z), v3 = u2f2(u.w);
    acc[0].x += v0.x * n; acc[0].y += v0.y * n;
    acc[1].x += v1.x * n; acc[1].y += v1.y * n;
    acc[2].x += v2.x * n; acc[2].y += v2.y * n;
    acc[3].x += v3.x * n; acc[3].y += v3.y * n;
}

// LESSONS LEDGER (measured):
//  R1: global-atomic bucket scatter = 65us (4B-scatter write-amp 58MB). Two-pass LDS binning wins.
//  R3: per-wave channel-split gathers = +94us (4x per-wave prologue tax).
//  R4: within-bucket src-sort = neutral (per-wave access order doesn't move cache behavior).
//  R5: grid-phased 64B channel stripes = +157us (stripe footprint amplification: FETCH 38->161MB;
//      slot metadata re-streamed x4 phases). Strided sub-row slices do NOT L2-pin.
//  => round-2 gather structure is the floor for the scatter phase; only fusion-level savings remain.

// ---------------- prep: conv_x || conv_w || edge binning, one kernel ----------------

__global__ __launch_bounds__(256) void prep_kernel(const float* __restrict__ x,
                                                   const float* __restrict__ W1,
                                                   const float* __restrict__ W2,
                                                   const int* __restrict__ src,
                                                   const int* __restrict__ dst,
                                                   ushort* __restrict__ xb,
                                                   ushort* __restrict__ w1t,
                                                   ushort* __restrict__ w2t,
                                                   int* __restrict__ bcnt,
                                                   int* __restrict__ binbuf) {
    __shared__ int vals[CHUNK];           // 16 KB: (src<<7)|(dst&127)
    __shared__ ushort lpos[CHUNK];        // 8 KB
    __shared__ ushort lbin[CHUNK];        // 8 KB (bin ids up to 390 need >8 bits)
    __shared__ int hist[NCOARSE];
    const int b = blockIdx.x;
    const int t = threadIdx.x;
    if (b < 6250) {
        int i = b * 256 + t;               // over N*128/4 float4s
        float4 v = ((const float4*)x)[i];
        ushort4 o; o.x = f2b(v.x); o.y = f2b(v.y); o.z = f2b(v.z); o.w = f2b(v.w);
        ((ushort4*)xb)[i] = o;
    } else if (b < 6506) {
        int i = (b - 6250) * 256 + t;      // 65536 total
        if (i < 32768) {
            int n = i >> 7, k = i & 127;
            w1t[i] = f2b(W1[k * HID_DIM + n]);
        } else {
            int j = i - 32768;
            int n = j >> 8, k = j & 255;
            w2t[j] = f2b(W2[k * OUT_DIM + n]);
        }
    } else {
        const int blk = b - 6506;
        const int e0 = blk * CHUNK;
        for (int i = t; i < NCOARSE; i += 256) hist[i] = 0;
        __syncthreads();
        for (int i = t; i < CHUNK; i += 256) {
            int s = src[e0 + i], d = dst[e0 + i];
            int bin = d >> 7;              // 128-node bins
            vals[i] = (s << 7) | (d & 127);
            lbin[i] = (ushort)bin;
            lpos[i] = (ushort)atomicAdd(&hist[bin], 1);
        }
        __syncthreads();
        for (int i = t; i < NCOARSE; i += 256) {
            int h = hist[i]; if (h > SEGCAP) h = SEGCAP;
            bcnt[i * NBLK1 + blk] = h;
        }
        for (int i = t; i < CHUNK; i += 256) {
            int bin = lbin[i];
            int p = lpos[i];
            if (p < SEGCAP) binbuf[((size_t)bin * NBLK1 + blk) * SEGCAP + p] = vals[i];
        }
    }
}

// ---------------- binpass2: one block per coarse bin (128 nodes) ----------------

__global__ __launch_bounds__(256) void binpass2_kernel(const int* __restrict__ bcnt,
                                                       const int* __restrict__ binbuf,
                                                       int* __restrict__ cnt,
                                                       float* __restrict__ dinv,
                                                       int* __restrict__ bucket) {
    __shared__ int lcnt[BINSZ];
    __shared__ int lm[NBLK1];
    __shared__ int lbuck[BINSZ * BUCKET_CAP];   // 32 KB
    const int bin = blockIdx.x;
    const int t = threadIdx.x;
    if (t < BINSZ) lcnt[t] = 0;
    if (t < NBLK1) lm[t] = bcnt[bin * NBLK1 + t];
    __syncthreads();
    const int* bb = binbuf + (size_t)bin * NBLK1 * SEGCAP;
    for (int f = t; f < NBLK1 * SEGCAP; f += 256) {
        int blk = f >> 5;        // SEGCAP = 32
        int sl = f & 31;
        if (sl < lm[blk]) {
            int v = bb[f];
            int dl = v & 127;
            int pos = atomicAdd(&lcnt[dl], 1);
            if (pos < BUCKET_CAP) lbuck[dl * BUCKET_CAP + pos] = v >> 7;
        }
    }
    __syncthreads();
    const int node0 = bin * BINSZ;
    int node = node0 + t;
    if (t < BINSZ && node < N_NODES) {
        int c = lcnt[t] > BUCKET_CAP ? BUCKET_CAP : lcnt[t];
        cnt[node] = c;
        dinv[node] = rsqrtf((float)c + 1.0f);
    }
    int nvalid = N_NODES - node0; if (nvalid > BINSZ) nvalid = BINSZ;
    if (nvalid <= 0) return;
    int total4 = (nvalid * BUCKET_CAP) >> 2;
    int4* d4 = (int4*)(bucket + (size_t)node0 * BUCKET_CAP);
    const int4* s4 = (const int4*)lbuck;
    for (int j = t; j < total4; j += 256) d4[j] = s4[j];
}

// ---------------- gemm12_fused: gather0 + (relu(aggx@W1+b1))@W2, one kernel ----------------
// Phase 0: each wave gathers 16 nodes (round-2 gather structure, one node at a
// time, full 64-lane participation) into an LDS tile Axs[64][136] (bf16).
// Saves the 25.6 MB aggxb HBM round-trip + one dispatch.
// Phase 1/2: unchanged champion MFMA path; A-fragments read from LDS.

__global__ __launch_bounds__(256, 2) void gemm12_fused(const int* __restrict__ cnt,
                                                       const int* __restrict__ bucket,
                                                       const float* __restrict__ dinv,
                                                       const ushort* __restrict__ xb,
                                                       const ushort* __restrict__ w1t,
                                                       const float* __restrict__ b1,
                                                       const ushort* __restrict__ w2t,
                                                       ushort* __restrict__ h2b) {
    __shared__ ushort Axs[GROWS * AXLD];  // 17 KB aggx tile
    __shared__ ushort Hs[GROWS * HLD];    // 33 KB H tile
    const int row0 = blockIdx.x * GROWS;
    const int wv = threadIdx.x >> 6;
    const int lane = threadIdx.x & 63;
    const int grp = lane >> 4, sub = lane & 15;
    const int l15 = lane & 15, q = lane >> 4;

    // ---- phase 0: gather aggx rows for this block's 64 nodes ----
    for (int j = 0; j < 16; ++j) {
        int w = row0 + wv * 16 + j;
        bool valid = w < N_NODES;
        int wc = valid ? w : 0;
        int n = valid ? cnt[wc] : 0;
        float dd = valid ? dinv[wc] : 0.f;
        int sv = 0; float nv = 0.f;
        if (lane < n) { sv = bucket[wc * BUCKET_CAP + lane]; nv = dinv[sv] * dd; }

        float2 acc[4];
        if (grp == 0) {   // self term, group 0 only
            uint4 su = ((const uint4*)(xb + (size_t)wc * IN_DIM))[sub];
            float sd = dd * dd;
            acc[0] = u2f2(su.x); acc[1] = u2f2(su.y); acc[2] = u2f2(su.z); acc[3] = u2f2(su.w);
#pragma unroll
            for (int k = 0; k < 4; ++k) { acc[k].x *= sd; acc[k].y *= sd; }
        } else {
#pragma unroll
            for (int k = 0; k < 4; ++k) acc[k] = {0.f, 0.f};
        }

        const int nr = (n + 15) & ~15;
        for (int i = 0; i < nr; i += 16) {
            int s0 = __shfl(sv, i + grp),      s1 = __shfl(sv, i + 4 + grp);
            int s2 = __shfl(sv, i + 8 + grp),  s3 = __shfl(sv, i + 12 + grp);
            float n0 = __shfl(nv, i + grp),     n1 = __shfl(nv, i + 4 + grp);
            float n2 = __shfl(nv, i + 8 + grp), n3 = __shfl(nv, i + 12 + grp);
            uint4 u0 = ((const uint4*)(xb + (size_t)s0 * IN_DIM))[sub];
            uint4 u1 = ((const uint4*)(xb + (size_t)s1 * IN_DIM))[sub];
            uint4 u2 = ((const uint4*)(xb + (size_t)s2 * IN_DIM))[sub];
            uint4 u3 = ((const uint4*)(xb + (size_t)s3 * IN_DIM))[sub];
            fma8(acc, u0, n0); fma8(acc, u1, n1); fma8(acc, u2, n2); fma8(acc, u3, n3);
        }
#pragma unroll
        for (int k = 0; k < 4; ++k) {
            acc[k].x += __shfl_down(acc[k].x, 32); acc[k].y += __shfl_down(acc[k].y, 32);
            acc[k].x += __shfl_down(acc[k].x, 16); acc[k].y += __shfl_down(acc[k].y, 16);
        }
        if (lane < 16) {
            uint4 o = {f2u2(acc[0].x, acc[0].y), f2u2(acc[1].x, acc[1].y),
                       f2u2(acc[2].x, acc[2].y), f2u2(acc[3].x, acc[3].y)};
            ((uint4*)(Axs + (wv * 16 + j) * AXLD))[sub] = o;
        }
    }
    __syncthreads();

    // ---- phase 1: H = relu(aggx @ W1 + b1) -> LDS ----
    short8 bf1[16];
#pragma unroll
    for (int kb = 0; kb < 4; ++kb)
#pragma unroll
        for (int t = 0; t < 4; ++t) {
            int col = wv * 64 + t * 16 + l15;
            bf1[kb * 4 + t] = *(const short8*)(w1t + (size_t)col * IN_DIM + kb * 32 + q * 8);
        }
    short8 af[4][4];
#pragma unroll
    for (int sub2 = 0; sub2 < 4; ++sub2) {
        const ushort* ab = Axs + (sub2 * 16 + l15) * AXLD + q * 8;
#pragma unroll
        for (int kb = 0; kb < 4; ++kb) af[sub2][kb] = *(const short8*)(ab + kb * 32);
    }
    f32x4 acc1[4][4] = {};
#pragma unroll
    for (int sub2 = 0; sub2 < 4; ++sub2)
#pragma unroll
        for (int kb = 0; kb < 4; ++kb)
#pragma unroll
            for (int t = 0; t < 4; ++t)
                acc1[sub2][t] = __builtin_amdgcn_mfma_f32_16x16x32_bf16(
                    af[sub2][kb], bf1[kb * 4 + t], acc1[sub2][t], 0, 0, 0);
#pragma unroll
    for (int t = 0; t < 4; ++t) {
        int col = wv * 64 + t * 16 + l15;
        float bias = b1[col];
#pragma unroll
        for (int sub2 = 0; sub2 < 4; ++sub2)
#pragma unroll
            for (int r = 0; r < 4; ++r) {
                int row = sub2 * 16 + q * 4 + r;
                float v = acc1[sub2][t][r] + bias;
                Hs[row * HLD + col] = f2b(v > 0.f ? v : 0.f);
            }
    }
    __syncthreads();

    // ---- phase 2: h2 = H @ W2 (A from LDS, B hoisted) ----
    short8 bf2[16];
#pragma unroll
    for (int kb = 0; kb < 8; ++kb)
#pragma unroll
        for (int t = 0; t < 2; ++t) {
            int col = wv * 32 + t * 16 + l15;
            bf2[kb * 2 + t] = *(const short8*)(w2t + (size_t)col * HID_DIM + kb * 32 + q * 8);
        }
    f32x4 acc2[4][2] = {};
#pragma unroll
    for (int sub2 = 0; sub2 < 4; ++sub2) {
        const ushort* hb = Hs + (sub2 * 16 + l15) * HLD + q * 8;
#pragma unroll
        for (int kb = 0; kb < 8; ++kb) {
            short8 a = *(const short8*)(hb + kb * 32);
#pragma unroll
            for (int t = 0; t < 2; ++t)
                acc2[sub2][t] = __builtin_amdgcn_mfma_f32_16x16x32_bf16(
                    a, bf2[kb * 2 + t], acc2[sub2][t], 0, 0, 0);
        }
    }
#pragma unroll
    for (int sub2 = 0; sub2 < 4; ++sub2)
#pragma unroll
        for (int t = 0; t < 2; ++t) {
            int col = wv * 32 + t * 16 + l15;
#pragma unroll
            for (int r = 0; r < 4; ++r) {
                int row = row0 + sub2 * 16 + q * 4 + r;
                if (row < N_NODES)
                    h2b[(size_t)row * OUT_DIM + col] = f2b(acc2[sub2][t][r]);
            }
        }
}

// ---------------- gather2: out = Ahat * h2 + b2 (bf16 in, fp32 out) ----------------

__global__ __launch_bounds__(256) void gather2_kernel(const int* __restrict__ cnt,
                                                      const int* __restrict__ bucket,
                                                      const float* __restrict__ dinv,
                                                      const ushort* __restrict__ h2b,
                                                      const float* __restrict__ b2,
                                                      float* __restrict__ out) {
    const int w = blockIdx.x * 4 + (threadIdx.x >> 6);
    const int lane = threadIdx.x & 63;
    const int grp = lane >> 4, sub = lane & 15;
    const int n = cnt[w];
    const float dd = dinv[w];
    int sv = 0; float nv = 0.f;
    if (lane < n) { sv = bucket[w * BUCKET_CAP + lane]; nv = dinv[sv] * dd; }

    float2 acc[4];
    if (grp == 0) {
        uint4 su = ((const uint4*)(h2b + (size_t)w * OUT_DIM))[sub];
        float sd = dd * dd;
        acc[0] = u2f2(su.x); acc[1] = u2f2(su.y); acc[2] = u2f2(su.z); acc[3] = u2f2(su.w);
#pragma unroll
        for (int j = 0; j < 4; ++j) { acc[j].x *= sd; acc[j].y *= sd; }
    } else {
#pragma unroll
        for (int j = 0; j < 4; ++j) acc[j] = {0.f, 0.f};
    }

    const int nr = (n + 15) & ~15;
    for (int i = 0; i < nr; i += 16) {
        int s0 = __shfl(sv, i + grp),      s1 = __shfl(sv, i + 4 + grp);
        int s2 = __shfl(sv, i + 8 + grp),  s3 = __shfl(sv, i + 12 + grp);
        float n0 = __shfl(nv, i + grp),     n1 = __shfl(nv, i + 4 + grp);
        float n2 = __shfl(nv, i + 8 + grp), n3 = __shfl(nv, i + 12 + grp);
        uint4 u0 = ((const uint4*)(h2b + (size_t)s0 * OUT_DIM))[sub];
        uint4 u1 = ((const uint4*)(h2b + (size_t)s1 * OUT_DIM))[sub];
        uint4 u2 = ((const uint4*)(h2b + (size_t)s2 * OUT_DIM))[sub];
        uint4 u3 = ((const uint4*)(h2b + (size_t)s3 * OUT_DIM))[sub];
        fma8(acc, u0, n0); fma8(acc, u1, n1); fma8(acc, u2, n2); fma8(acc, u3, n3);
    }
#pragma unroll
    for (int j = 0; j < 4; ++j) {
        acc[j].x += __shfl_down(acc[j].x, 32); acc[j].y += __shfl_down(acc[j].y, 32);
        acc[j].x += __shfl_down(acc[j].x, 16); acc[j].y += __shfl_down(acc[j].y, 16);
    }
    if (lane < 16) {
        const float4* bp = (const float4*)b2;
        float4 b0 = bp[sub * 2], b1v = bp[sub * 2 + 1];
        float4 o0 = {acc[0].x + b0.x, acc[0].y + b0.y, acc[1].x + b0.z, acc[1].y + b0.w};
        float4 o1 = {acc[2].x + b1v.x, acc[2].y + b1v.y, acc[3].x + b1v.z, acc[3].y + b1v.w};
        float4* op = (float4*)(out + (size_t)w * OUT_DIM);
        op[sub * 2] = o0;
        op[sub * 2 + 1] = o1;
    }
}

extern "C" void kernel_launch(void* const* d_in, const int* in_sizes, int n_in,
                              void* d_out, int out_size, void* d_ws, size_t ws_size,
                              hipStream_t stream) {
    const float* x  = (const float*)d_in[0];
    const int*   ei = (const int*)d_in[1];
    const float* W1 = (const float*)d_in[2];
    const float* b1 = (const float*)d_in[3];
    const float* W2 = (const float*)d_in[4];
    const float* b2 = (const float*)d_in[5];
    float* out = (float*)d_out;

    const int* src = ei;             // edge_index[0]
    const int* dst = ei + N_EDGES;   // edge_index[1]

    // workspace layout (bytes):
    //  bcnt   : [0, 312800)                 int[391*200]
    //  cnt    : [320000, 520000)            int[50000]
    //  dinv   : [520000, 720000)            float[50000]
    //  bucket : [720000, 13520000)          int[50000*64]
    //  binbuf : [13520000, 23529600)        int[391*200*32]
    //  xb     : [23532800, 36332800)        bf16[50000*128]
    //  w1t    : [36332800, 36398336)        bf16[256*128]
    //  w2t    : [36398336, 36463872)        bf16[128*256]
    //  h2b    : [36463872, 49263872)        bf16[50000*128]
    char* ws = (char*)d_ws;
    int*    bcnt   = (int*)(ws);
    int*    cnt    = (int*)(ws + 320000);
    float*  dinv   = (float*)(ws + 520000);
    int*    bucket = (int*)(ws + 720000);
    int*    binbuf = (int*)(ws + 13520000);
    ushort* xb     = (ushort*)(ws + 23532800);
    ushort* w1t    = (ushort*)(ws + 36332800);
    ushort* w2t    = (ushort*)(ws + 36398336);
    ushort* h2b    = (ushort*)(ws + 36463872);

    // prep (conv_x || conv_w || binning) -> bucket build
    prep_kernel<<<6706, 256, 0, stream>>>(x, W1, W2, src, dst, xb, w1t, w2t, bcnt, binbuf);
    binpass2_kernel<<<NCOARSE, 256, 0, stream>>>(bcnt, binbuf, cnt, dinv, bucket);

    // fused: layer-1 aggregate (LDS tile) + transform L1+L2 (H stays in LDS)
    gemm12_fused<<<(N_NODES + GROWS - 1) / GROWS, 256, 0, stream>>>(
        cnt, bucket, dinv, xb, w1t, b1, w2t, h2b);

    // layer 2 aggregate (self-loop + b2 fused)
    gather2_kernel<<<N_NODES / 4, 256, 0, stream>>>(cnt, bucket, dinv, h2b, b2, out);
}

// Round 7
// 204.313 us; speedup vs baseline: 1.7834x; 1.1542x over previous
//
#include <hip/hip_runtime.h>

#define N_NODES 50000
#define N_EDGES 800000
#define IN_DIM  128
#define HID_DIM 256
#define OUT_DIM 128
#define BUCKET_CAP 64    // in-degree ~ Poisson(16); P(deg>64) ~ 2e-18 over 50k nodes
#define NCOARSE 391      // ceil(50000/128) coarse bins of 128 dst nodes
#define BINSZ 128        // nodes per coarse bin
#define CHUNK 4000       // edges per binning block
#define NBLK1 200        // 200 * 4000 = 800000
#define SEGCAP 32        // per-(block,bin) capacity: Poisson(10.24) + ~6.8 sigma
#define HLD 264          // LDS row stride (ushorts) for H tile: 256 + 8 pad (528B, 16B-aligned)
#define GROWS 64         // rows per gemm12 block

typedef __attribute__((ext_vector_type(8))) short short8;
typedef __attribute__((ext_vector_type(4))) float f32x4;

// ---- bf16 helpers (RNE) ----
__device__ inline ushort f2b(float f) {
    union { float f; unsigned u; } v; v.f = f;
    return (ushort)((v.u + 0x7FFFu + ((v.u >> 16) & 1u)) >> 16);
}
__device__ inline float b2f(ushort h) {
    union { unsigned u; float f; } v; v.u = ((unsigned)h) << 16;
    return v.f;
}
__device__ inline float2 u2f2(unsigned u) {
    float2 r; r.x = b2f((ushort)(u & 0xFFFFu)); r.y = b2f((ushort)(u >> 16)); return r;
}
__device__ inline unsigned f2u2(float a, float b) {
    return (unsigned)f2b(a) | ((unsigned)f2b(b) << 16);
}
__device__ inline void fma8(float2* acc, uint4 u, float n) {
    float2 v0 = u2f2(u.x), v1 = u2f2(u.y), v2 = u2f2(u.z), v3 = u2f2(u.w);
    acc[0].x += v0.x * n; acc[0].y += v0.y * n;
    acc[1].x += v1.x * n; acc[1].y += v1.y * n;
    acc[2].x += v2.x * n; acc[2].y += v2.y * n;
    acc[3].x += v3.x * n; acc[3].y += v3.y * n;
}

// LESSONS LEDGER (measured on MI355X):
//  R1: global-atomic bucket scatter = 65us (4B-scatter write-amp 58MB). Two-pass LDS binning wins.
//  R3: per-wave channel-split gathers = +94us (4x per-wave prologue tax).
//  R4: within-bucket src-sort = neutral (per-wave access order doesn't move cache behavior).
//  R5: grid-phased 64B channel stripes = +157us (stripe footprint amplification, FETCH 38->161MB).
//  R6: fusing gather into gemm = +29us (gather is LATENCY-bound; needs ~24 waves/CU TLP,
//      dies at gemm occupancy under a pre-MFMA barrier).
//  => this configuration is the measured floor for every phase; fills (~84us) are harness-fixed.

// ---------------- prep: conv_x || conv_w || edge binning, one kernel ----------------

__global__ __launch_bounds__(256) void prep_kernel(const float* __restrict__ x,
                                                   const float* __restrict__ W1,
                                                   const float* __restrict__ W2,
                                                   const int* __restrict__ src,
                                                   const int* __restrict__ dst,
                                                   ushort* __restrict__ xb,
                                                   ushort* __restrict__ w1t,
                                                   ushort* __restrict__ w2t,
                                                   int* __restrict__ bcnt,
                                                   int* __restrict__ binbuf) {
    __shared__ int vals[CHUNK];           // 16 KB: (src<<7)|(dst&127)
    __shared__ ushort lpos[CHUNK];        // 8 KB
    __shared__ ushort lbin[CHUNK];        // 8 KB (bin ids up to 390 need >8 bits)
    __shared__ int hist[NCOARSE];
    const int b = blockIdx.x;
    const int t = threadIdx.x;
    if (b < 6250) {
        int i = b * 256 + t;               // over N*128/4 float4s
        float4 v = ((const float4*)x)[i];
        ushort4 o; o.x = f2b(v.x); o.y = f2b(v.y); o.z = f2b(v.z); o.w = f2b(v.w);
        ((ushort4*)xb)[i] = o;
    } else if (b < 6506) {
        int i = (b - 6250) * 256 + t;      // 65536 total
        if (i < 32768) {
            int n = i >> 7, k = i & 127;
            w1t[i] = f2b(W1[k * HID_DIM + n]);
        } else {
            int j = i - 32768;
            int n = j >> 8, k = j & 255;
            w2t[j] = f2b(W2[k * OUT_DIM + n]);
        }
    } else {
        const int blk = b - 6506;
        const int e0 = blk * CHUNK;
        for (int i = t; i < NCOARSE; i += 256) hist[i] = 0;
        __syncthreads();
        for (int i = t; i < CHUNK; i += 256) {
            int s = src[e0 + i], d = dst[e0 + i];
            int bin = d >> 7;              // 128-node bins
            vals[i] = (s << 7) | (d & 127);
            lbin[i] = (ushort)bin;
            lpos[i] = (ushort)atomicAdd(&hist[bin], 1);
        }
        __syncthreads();
        for (int i = t; i < NCOARSE; i += 256) {
            int h = hist[i]; if (h > SEGCAP) h = SEGCAP;
            bcnt[i * NBLK1 + blk] = h;
        }
        for (int i = t; i < CHUNK; i += 256) {
            int bin = lbin[i];
            int p = lpos[i];
            if (p < SEGCAP) binbuf[((size_t)bin * NBLK1 + blk) * SEGCAP + p] = vals[i];
        }
    }
}

// ---------------- binpass2: one block per coarse bin (128 nodes) ----------------
// 128-node bins: 391 blocks x 33KB LDS -> up to 4 blocks/CU, 25 scan iters.

__global__ __launch_bounds__(256) void binpass2_kernel(const int* __restrict__ bcnt,
                                                       const int* __restrict__ binbuf,
                                                       int* __restrict__ cnt,
                                                       float* __restrict__ dinv,
                                                       int* __restrict__ bucket) {
    __shared__ int lcnt[BINSZ];
    __shared__ int lm[NBLK1];
    __shared__ int lbuck[BINSZ * BUCKET_CAP];   // 32 KB
    const int bin = blockIdx.x;
    const int t = threadIdx.x;
    if (t < BINSZ) lcnt[t] = 0;
    if (t < NBLK1) lm[t] = bcnt[bin * NBLK1 + t];
    __syncthreads();
    const int* bb = binbuf + (size_t)bin * NBLK1 * SEGCAP;
    for (int f = t; f < NBLK1 * SEGCAP; f += 256) {
        int blk = f >> 5;        // SEGCAP = 32
        int sl = f & 31;
        if (sl < lm[blk]) {
            int v = bb[f];
            int dl = v & 127;
            int pos = atomicAdd(&lcnt[dl], 1);
            if (pos < BUCKET_CAP) lbuck[dl * BUCKET_CAP + pos] = v >> 7;
        }
    }
    __syncthreads();
    const int node0 = bin * BINSZ;
    int node = node0 + t;
    if (t < BINSZ && node < N_NODES) {
        int c = lcnt[t] > BUCKET_CAP ? BUCKET_CAP : lcnt[t];
        cnt[node] = c;
        dinv[node] = rsqrtf((float)c + 1.0f);
    }
    int nvalid = N_NODES - node0; if (nvalid > BINSZ) nvalid = BINSZ;
    if (nvalid <= 0) return;
    int total4 = (nvalid * BUCKET_CAP) >> 2;
    int4* d4 = (int4*)(bucket + (size_t)node0 * BUCKET_CAP);
    const int4* s4 = (const int4*)lbuck;
    for (int j = t; j < total4; j += 256) d4[j] = s4[j];
}

// ---------------- gather0: aggx = Ahat * x (bf16 in/out, fp32 acc) ----------------
// one wave per dst node; 16 lanes per edge, dwordx4 loads, 4 edges/instruction.

__global__ __launch_bounds__(256) void gather0_kernel(const int* __restrict__ cnt,
                                                      const int* __restrict__ bucket,
                                                      const float* __restrict__ dinv,
                                                      const ushort* __restrict__ xb,
                                                      ushort* __restrict__ aggxb) {
    const int w = blockIdx.x * 4 + (threadIdx.x >> 6);
    const int lane = threadIdx.x & 63;
    const int grp = lane >> 4, sub = lane & 15;
    const int n = cnt[w];
    const float dd = dinv[w];
    int sv = 0; float nv = 0.f;
    if (lane < n) { sv = bucket[w * BUCKET_CAP + lane]; nv = dinv[sv] * dd; }

    float2 acc[4];
    if (grp == 0) {   // self term, group 0 only
        uint4 su = ((const uint4*)(xb + (size_t)w * IN_DIM))[sub];
        float sd = dd * dd;
        acc[0] = u2f2(su.x); acc[1] = u2f2(su.y); acc[2] = u2f2(su.z); acc[3] = u2f2(su.w);
#pragma unroll
        for (int j = 0; j < 4; ++j) { acc[j].x *= sd; acc[j].y *= sd; }
    } else {
#pragma unroll
        for (int j = 0; j < 4; ++j) acc[j] = {0.f, 0.f};
    }

    const int nr = (n + 15) & ~15;
    for (int i = 0; i < nr; i += 16) {
        int s0 = __shfl(sv, i + grp),      s1 = __shfl(sv, i + 4 + grp);
        int s2 = __shfl(sv, i + 8 + grp),  s3 = __shfl(sv, i + 12 + grp);
        float n0 = __shfl(nv, i + grp),     n1 = __shfl(nv, i + 4 + grp);
        float n2 = __shfl(nv, i + 8 + grp), n3 = __shfl(nv, i + 12 + grp);
        uint4 u0 = ((const uint4*)(xb + (size_t)s0 * IN_DIM))[sub];
        uint4 u1 = ((const uint4*)(xb + (size_t)s1 * IN_DIM))[sub];
        uint4 u2 = ((const uint4*)(xb + (size_t)s2 * IN_DIM))[sub];
        uint4 u3 = ((const uint4*)(xb + (size_t)s3 * IN_DIM))[sub];
        fma8(acc, u0, n0); fma8(acc, u1, n1); fma8(acc, u2, n2); fma8(acc, u3, n3);
    }
#pragma unroll
    for (int j = 0; j < 4; ++j) {
        acc[j].x += __shfl_down(acc[j].x, 32); acc[j].y += __shfl_down(acc[j].y, 32);
        acc[j].x += __shfl_down(acc[j].x, 16); acc[j].y += __shfl_down(acc[j].y, 16);
    }
    if (lane < 16) {
        uint4 o = {f2u2(acc[0].x, acc[0].y), f2u2(acc[1].x, acc[1].y),
                   f2u2(acc[2].x, acc[2].y), f2u2(acc[3].x, acc[3].y)};
        ((uint4*)(aggxb + (size_t)w * IN_DIM))[sub] = o;
    }
}

// ---------------- gemm12 (MFMA, fused): h2b = (relu(aggx@W1 + b1)) @ W2 ----------------
// Block = 64 rows, 4 waves; wave covers 64 cols (phase1) / 32 cols (phase2).
// B-fragments hoisted into registers ONCE and reused over 4 row-subtiles.
// __launch_bounds__(256,2): 256-VGPR cap so the frags actually stay live.

__global__ __launch_bounds__(256, 2) void gemm12_mfma(const ushort* __restrict__ aggxb,
                                                      const ushort* __restrict__ w1t,
                                                      const float* __restrict__ b1,
                                                      const ushort* __restrict__ w2t,
                                                      ushort* __restrict__ h2b) {
    __shared__ ushort Hs[GROWS * HLD];   // 33 KB
    const int row0 = blockIdx.x * GROWS;
    const int wv = threadIdx.x >> 6;
    const int lane = threadIdx.x & 63;
    const int l15 = lane & 15, q = lane >> 4;

    // ---- phase 1: H = relu(aggx @ W1 + b1) -> LDS ----
    short8 bf1[16];
#pragma unroll
    for (int kb = 0; kb < 4; ++kb)
#pragma unroll
        for (int t = 0; t < 4; ++t) {
            int col = wv * 64 + t * 16 + l15;
            bf1[kb * 4 + t] = *(const short8*)(w1t + (size_t)col * IN_DIM + kb * 32 + q * 8);
        }
    short8 af[4][4];
#pragma unroll
    for (int sub = 0; sub < 4; ++sub) {
        int ar = row0 + sub * 16 + l15;
        if (ar >= N_NODES) ar = N_NODES - 1;
        const ushort* ab = aggxb + (size_t)ar * IN_DIM + q * 8;
#pragma unroll
        for (int kb = 0; kb < 4; ++kb) af[sub][kb] = *(const short8*)(ab + kb * 32);
    }
    f32x4 acc1[4][4] = {};
#pragma unroll
    for (int sub = 0; sub < 4; ++sub)
#pragma unroll
        for (int kb = 0; kb < 4; ++kb)
#pragma unroll
            for (int t = 0; t < 4; ++t)
                acc1[sub][t] = __builtin_amdgcn_mfma_f32_16x16x32_bf16(
                    af[sub][kb], bf1[kb * 4 + t], acc1[sub][t], 0, 0, 0);
#pragma unroll
    for (int t = 0; t < 4; ++t) {
        int col = wv * 64 + t * 16 + l15;
        float bias = b1[col];
#pragma unroll
        for (int sub = 0; sub < 4; ++sub)
#pragma unroll
            for (int r = 0; r < 4; ++r) {
                int row = sub * 16 + q * 4 + r;
                float v = acc1[sub][t][r] + bias;
                Hs[row * HLD + col] = f2b(v > 0.f ? v : 0.f);
            }
    }
    __syncthreads();

    // ---- phase 2: h2 = H @ W2 (A from LDS, B hoisted) ----
    short8 bf2[16];
#pragma unroll
    for (int kb = 0; kb < 8; ++kb)
#pragma unroll
        for (int t = 0; t < 2; ++t) {
            int col = wv * 32 + t * 16 + l15;
            bf2[kb * 2 + t] = *(const short8*)(w2t + (size_t)col * HID_DIM + kb * 32 + q * 8);
        }
    f32x4 acc2[4][2] = {};
#pragma unroll
    for (int sub = 0; sub < 4; ++sub) {
        const ushort* hb = Hs + (sub * 16 + l15) * HLD + q * 8;
#pragma unroll
        for (int kb = 0; kb < 8; ++kb) {
            short8 a = *(const short8*)(hb + kb * 32);
#pragma unroll
            for (int t = 0; t < 2; ++t)
                acc2[sub][t] = __builtin_amdgcn_mfma_f32_16x16x32_bf16(
                    a, bf2[kb * 2 + t], acc2[sub][t], 0, 0, 0);
        }
    }
#pragma unroll
    for (int sub = 0; sub < 4; ++sub)
#pragma unroll
        for (int t = 0; t < 2; ++t) {
            int col = wv * 32 + t * 16 + l15;
#pragma unroll
            for (int r = 0; r < 4; ++r) {
                int row = row0 + sub * 16 + q * 4 + r;
                if (row < N_NODES)
                    h2b[(size_t)row * OUT_DIM + col] = f2b(acc2[sub][t][r]);
            }
        }
}

// ---------------- gather2: out = Ahat * h2 + b2 (bf16 in, fp32 out) ----------------

__global__ __launch_bounds__(256) void gather2_kernel(const int* __restrict__ cnt,
                                                      const int* __restrict__ bucket,
                                                      const float* __restrict__ dinv,
                                                      const ushort* __restrict__ h2b,
                                                      const float* __restrict__ b2,
                                                      float* __restrict__ out) {
    const int w = blockIdx.x * 4 + (threadIdx.x >> 6);
    const int lane = threadIdx.x & 63;
    const int grp = lane >> 4, sub = lane & 15;
    const int n = cnt[w];
    const float dd = dinv[w];
    int sv = 0; float nv = 0.f;
    if (lane < n) { sv = bucket[w * BUCKET_CAP + lane]; nv = dinv[sv] * dd; }

    float2 acc[4];
    if (grp == 0) {
        uint4 su = ((const uint4*)(h2b + (size_t)w * OUT_DIM))[sub];
        float sd = dd * dd;
        acc[0] = u2f2(su.x); acc[1] = u2f2(su.y); acc[2] = u2f2(su.z); acc[3] = u2f2(su.w);
#pragma unroll
        for (int j = 0; j < 4; ++j) { acc[j].x *= sd; acc[j].y *= sd; }
    } else {
#pragma unroll
        for (int j = 0; j < 4; ++j) acc[j] = {0.f, 0.f};
    }

    const int nr = (n + 15) & ~15;
    for (int i = 0; i < nr; i += 16) {
        int s0 = __shfl(sv, i + grp),      s1 = __shfl(sv, i + 4 + grp);
        int s2 = __shfl(sv, i + 8 + grp),  s3 = __shfl(sv, i + 12 + grp);
        float n0 = __shfl(nv, i + grp),     n1 = __shfl(nv, i + 4 + grp);
        float n2 = __shfl(nv, i + 8 + grp), n3 = __shfl(nv, i + 12 + grp);
        uint4 u0 = ((const uint4*)(h2b + (size_t)s0 * OUT_DIM))[sub];
        uint4 u1 = ((const uint4*)(h2b + (size_t)s1 * OUT_DIM))[sub];
        uint4 u2 = ((const uint4*)(h2b + (size_t)s2 * OUT_DIM))[sub];
        uint4 u3 = ((const uint4*)(h2b + (size_t)s3 * OUT_DIM))[sub];
        fma8(acc, u0, n0); fma8(acc, u1, n1); fma8(acc, u2, n2); fma8(acc, u3, n3);
    }
#pragma unroll
    for (int j = 0; j < 4; ++j) {
        acc[j].x += __shfl_down(acc[j].x, 32); acc[j].y += __shfl_down(acc[j].y, 32);
        acc[j].x += __shfl_down(acc[j].x, 16); acc[j].y += __shfl_down(acc[j].y, 16);
    }
    if (lane < 16) {
        const float4* bp = (const float4*)b2;
        float4 b0 = bp[sub * 2], b1v = bp[sub * 2 + 1];
        float4 o0 = {acc[0].x + b0.x, acc[0].y + b0.y, acc[1].x + b0.z, acc[1].y + b0.w};
        float4 o1 = {acc[2].x + b1v.x, acc[2].y + b1v.y, acc[3].x + b1v.z, acc[3].y + b1v.w};
        float4* op = (float4*)(out + (size_t)w * OUT_DIM);
        op[sub * 2] = o0;
        op[sub * 2 + 1] = o1;
    }
}

extern "C" void kernel_launch(void* const* d_in, const int* in_sizes, int n_in,
                              void* d_out, int out_size, void* d_ws, size_t ws_size,
                              hipStream_t stream) {
    const float* x  = (const float*)d_in[0];
    const int*   ei = (const int*)d_in[1];
    const float* W1 = (const float*)d_in[2];
    const float* b1 = (const float*)d_in[3];
    const float* W2 = (const float*)d_in[4];
    const float* b2 = (const float*)d_in[5];
    float* out = (float*)d_out;

    const int* src = ei;             // edge_index[0]
    const int* dst = ei + N_EDGES;   // edge_index[1]

    // workspace layout (bytes):
    //  bcnt   : [0, 312800)                 int[391*200]
    //  cnt    : [320000, 520000)            int[50000]
    //  dinv   : [520000, 720000)            float[50000]
    //  bucket : [720000, 13520000)          int[50000*64]
    //  binbuf : [13520000, 23529600)        int[391*200*32]
    //  xb     : [23532800, 36332800)        bf16[50000*128]
    //  w1t    : [36332800, 36398336)        bf16[256*128]
    //  w2t    : [36398336, 36463872)        bf16[128*256]
    //  aggxb  : [36463872, 49263872)        bf16[50000*128]
    //  h2b    : [49263872, 62063872)        bf16[50000*128]
    char* ws = (char*)d_ws;
    int*    bcnt   = (int*)(ws);
    int*    cnt    = (int*)(ws + 320000);
    float*  dinv   = (float*)(ws + 520000);
    int*    bucket = (int*)(ws + 720000);
    int*    binbuf = (int*)(ws + 13520000);
    ushort* xb     = (ushort*)(ws + 23532800);
    ushort* w1t    = (ushort*)(ws + 36332800);
    ushort* w2t    = (ushort*)(ws + 36398336);
    ushort* aggxb  = (ushort*)(ws + 36463872);
    ushort* h2b    = (ushort*)(ws + 49263872);

    // prep (conv_x || conv_w || binning) -> bucket build
    prep_kernel<<<6706, 256, 0, stream>>>(x, W1, W2, src, dst, xb, w1t, w2t, bcnt, binbuf);
    binpass2_kernel<<<NCOARSE, 256, 0, stream>>>(bcnt, binbuf, cnt, dinv, bucket);

    // layer 1 aggregate (one wave/node), then fused transform L1+L2 (H stays in LDS)
    gather0_kernel<<<N_NODES / 4, 256, 0, stream>>>(cnt, bucket, dinv, xb, aggxb);
    gemm12_mfma<<<(N_NODES + GROWS - 1) / GROWS, 256, 0, stream>>>(aggxb, w1t, b1, w2t, h2b);

    // layer 2 aggregate (self-loop + b2 fused)
    gather2_kernel<<<N_NODES / 4, 256, 0, stream>>>(cnt, bucket, dinv, h2b, b2, out);
}